// Round 1
// 426.888 us; speedup vs baseline: 1.0481x; 1.0481x over previous
//
#include <hip/hip_runtime.h>
#include <hip/hip_fp16.h>

// Trilinear grid-sample, two-pass:
//  Pass 1: transform feats [B,F,D,H,W] f32 -> T [B,D,H,W,F] fp16 in d_ws.
//          Channels-last => the 16 values a sample needs per (z,y) row
//          (x0,x1 x 8 features) are 32B CONTIGUOUS. fp16 halves the L3
//          footprint: 128 MiB, fully Infinity-Cache resident.
//          feats reads are NONTEMPORAL so the 256 MiB single-touch stream
//          does not evict the freshly written T lines from the memory-side
//          Infinity Cache.
//  Pass 2: gather + trilerp. All 8 dwordx4 gathers are issued before any
//          arithmetic (MLP=8). grid reads and out writes are nontemporal
//          (single touch); only T goes through the caches.

#define NB 4
#define NF 8
#define ND 128
#define NH 128
#define NW 128
#define HG 512
#define WG 512

typedef float        __attribute__((ext_vector_type(4))) f32x4;
typedef unsigned int __attribute__((ext_vector_type(4))) u32x4;

__global__ __launch_bounds__(256) void transform_kernel(
    const float* __restrict__ feats, __half* __restrict__ T)
{
    const size_t S = (size_t)ND * NH * NW;           // 2,097,152 spatial
    size_t tid = (size_t)blockIdx.x * blockDim.x + threadIdx.x; // 0..NB*S/4-1
    size_t b  = tid / (S / 4);
    size_t s4 = (tid - b * (S / 4)) * 4;             // 4 spatial positions

    const float* fb = feats + b * NF * S;
    __half* tb = T + (b * S + s4) * NF;              // 16B-aligned (s4*16B)

    f32x4 vals[NF];
#pragma unroll
    for (int f = 0; f < NF; ++f)
        vals[f] = __builtin_nontemporal_load(
            (const f32x4*)(fb + (size_t)f * S + s4));

#pragma unroll
    for (int i = 0; i < 4; ++i) {
        u32x4 hv;
#pragma unroll
        for (int f = 0; f < 4; ++f) {
            __half2 h = __floats2half2_rn(vals[2 * f][i], vals[2 * f + 1][i]);
            hv[f] = *(const unsigned*)&h;
        }
        *(u32x4*)(tb + (size_t)i * NF) = hv;         // cached: want T in L3
    }
}

__device__ __forceinline__ void pair_accum(
    const u32x4& lov, const u32x4& hiv, bool hi,
    float wr, float um, float u, float acc[NF])
{
    u32x4 c0 = hi ? hiv : lov;                       // x-edge clamp (ix0==127)
    const u32x4& c1 = hiv;
#pragma unroll
    for (int j = 0; j < 4; ++j) {
        unsigned u0 = c0[j], u1 = c1[j];
        float2 f0 = __half22float2(*(const __half2*)&u0);
        float2 f1 = __half22float2(*(const __half2*)&u1);
        acc[2 * j]     = fmaf(wr, fmaf(u, f1.x, um * f0.x), acc[2 * j]);
        acc[2 * j + 1] = fmaf(wr, fmaf(u, f1.y, um * f0.y), acc[2 * j + 1]);
    }
}

__global__ __launch_bounds__(256) void trilerp_half_kernel(
    const __half* __restrict__ T,
    const float* __restrict__ grid,
    float* __restrict__ out)
{
    const int P = HG * WG;                           // 2^18
    int idx = blockIdx.x * blockDim.x + threadIdx.x; // 0..2^20-1
    int b = idx >> 18;
    int p = idx & (P - 1);

    const float* g = grid + (size_t)idx * 3;
    float x = __builtin_nontemporal_load(g + 0);
    float y = __builtin_nontemporal_load(g + 1);
    float z = __builtin_nontemporal_load(g + 2);

    x = fminf(fmaxf(x, -1.0f), 1.0f);
    y = fminf(fmaxf(y, -1.0f), 1.0f);
    z = fminf(fmaxf(z, -1.0f), 1.0f);
    x = (x + 1.0f) * 0.5f * (float)(NW - 1);
    y = (y + 1.0f) * 0.5f * (float)(NH - 1);
    z = (z + 1.0f) * 0.5f * (float)(ND - 1);

    float xf = floorf(x), yf = floorf(y), zf = floorf(z);
    float u = x - xf, v = y - yf, w = z - zf;
    float um = 1.0f - u, vm = 1.0f - v, wm = 1.0f - w;

    int ix0 = min(max((int)xf, 0), NW - 1);
    int iy0 = min(max((int)yf, 0), NH - 1);
    int iy1 = min(iy0 + 1, NH - 1);
    int iz0 = min(max((int)zf, 0), ND - 1);
    int iz1 = min(iz0 + 1, ND - 1);

    int xb = min(ix0, NW - 2);                       // float2-block base
    bool hi = (ix0 != xb);                           // ix0==127 -> both = upper

    const __half* tb = T + (size_t)b * ((size_t)ND * NH * NW) * NF;
    size_t r00 = ((size_t)(iz0 * NH + iy0) * NW + xb) * NF;  // z0 y0
    size_t r01 = ((size_t)(iz0 * NH + iy1) * NW + xb) * NF;  // z0 y1
    size_t r10 = ((size_t)(iz1 * NH + iy0) * NW + xb) * NF;  // z1 y0
    size_t r11 = ((size_t)(iz1 * NH + iy1) * NW + xb) * NF;  // z1 y1

    // Issue ALL 8 gathers before any arithmetic -> MLP = 8 per thread.
    u32x4 L[8];
    L[0] = *(const u32x4*)(tb + r00);
    L[1] = *(const u32x4*)(tb + r00 + NF);
    L[2] = *(const u32x4*)(tb + r01);
    L[3] = *(const u32x4*)(tb + r01 + NF);
    L[4] = *(const u32x4*)(tb + r10);
    L[5] = *(const u32x4*)(tb + r10 + NF);
    L[6] = *(const u32x4*)(tb + r11);
    L[7] = *(const u32x4*)(tb + r11 + NF);

    float acc[NF];
#pragma unroll
    for (int f = 0; f < NF; ++f) acc[f] = 0.0f;

    pair_accum(L[0], L[1], hi, wm * vm, um, u, acc);
    pair_accum(L[2], L[3], hi, wm * v,  um, u, acc);
    pair_accum(L[4], L[5], hi, w  * vm, um, u, acc);
    pair_accum(L[6], L[7], hi, w  * v,  um, u, acc);

    float* o = out + (size_t)b * NF * P + p;
#pragma unroll
    for (int f = 0; f < NF; ++f)
        __builtin_nontemporal_store(acc[f], o + (size_t)f * P);
}

// ---- fallback (round-1 kernel) if ws_size is too small ----
__global__ __launch_bounds__(256) void trilerp_f32_kernel(
    const float* __restrict__ feats,
    const float* __restrict__ grid,
    float* __restrict__ out)
{
    const int P = HG * WG;
    int idx = blockIdx.x * blockDim.x + threadIdx.x;
    int b = idx >> 18;
    int p = idx & (P - 1);

    const float* g = grid + (size_t)idx * 3;
    float x = g[0], y = g[1], z = g[2];
    x = fminf(fmaxf(x, -1.0f), 1.0f);
    y = fminf(fmaxf(y, -1.0f), 1.0f);
    z = fminf(fmaxf(z, -1.0f), 1.0f);
    x = (x + 1.0f) * 0.5f * (float)(NW - 1);
    y = (y + 1.0f) * 0.5f * (float)(NH - 1);
    z = (z + 1.0f) * 0.5f * (float)(ND - 1);

    float xf = floorf(x), yf = floorf(y), zf = floorf(z);
    float u = x - xf, v = y - yf, w = z - zf;

    int ix0 = min(max((int)xf, 0), NW - 1);
    int ix1 = min(ix0 + 1, NW - 1);
    int iy0 = min(max((int)yf, 0), NH - 1);
    int iy1 = min(iy0 + 1, NH - 1);
    int iz0 = min(max((int)zf, 0), ND - 1);
    int iz1 = min(iz0 + 1, ND - 1);

    float um = 1.0f - u, vm = 1.0f - v, wm = 1.0f - w;
    float w000 = um * vm * wm, w100 = u * vm * wm;
    float w010 = um * v * wm,  w110 = u * v * wm;
    float w001 = um * vm * w,  w101 = u * vm * w;
    float w011 = um * v * w,   w111 = u * v * w;

    int off00 = (iz0 * NH + iy0) * NW;
    int off01 = (iz0 * NH + iy1) * NW;
    int off10 = (iz1 * NH + iy0) * NW;
    int off11 = (iz1 * NH + iy1) * NW;

    const size_t fstride = (size_t)ND * NH * NW;
    const float* fb = feats + (size_t)b * NF * fstride;
    float* o = out + (size_t)b * NF * P + p;

#pragma unroll
    for (int f = 0; f < NF; ++f) {
        const float* fp = fb + (size_t)f * fstride;
        float r = w000 * fp[off00 + ix0] + w100 * fp[off00 + ix1]
                + w010 * fp[off01 + ix0] + w110 * fp[off01 + ix1]
                + w001 * fp[off10 + ix0] + w101 * fp[off10 + ix1]
                + w011 * fp[off11 + ix0] + w111 * fp[off11 + ix1];
        o[(size_t)f * P] = r;
    }
}

extern "C" void kernel_launch(void* const* d_in, const int* in_sizes, int n_in,
                              void* d_out, int out_size, void* d_ws, size_t ws_size,
                              hipStream_t stream) {
    const float* feats = (const float*)d_in[0];
    const float* grid  = (const float*)d_in[1];
    float* out = (float*)d_out;

    const size_t needed = (size_t)NB * ND * NH * NW * NF * sizeof(__half); // 128 MiB

    if (ws_size >= needed) {
        __half* T = (__half*)d_ws;
        const int tthreads = NB * ND * NH * NW / 4;          // 2^21
        transform_kernel<<<tthreads / 256, 256, 0, stream>>>(feats, T);
        const int total = NB * HG * WG;                      // 2^20
        trilerp_half_kernel<<<total / 256, 256, 0, stream>>>(T, grid, out);
    } else {
        const int total = NB * HG * WG;
        trilerp_f32_kernel<<<total / 256, 256, 0, stream>>>(feats, grid, out);
    }
}